// Round 6
// baseline (441.697 us; speedup 1.0000x reference)
//
#include <hip/hip_runtime.h>

#define N_NODES   100000
#define N_EDGES   1600000
#define NFEAT     128
#define N_GRAPHS  1024

// ---- bucketed CSR build ----
#define BSHIFT  6
#define NBUCK   1563                 // ceil(100000 / 64)
#define NSUB    8                    // sub-buckets (XCD-heuristic partition)
#define SUBCAP  256                  // mean 128, +11 sigma headroom
#define CURSTRIDE 16                 // one cursor per 64B line

typedef unsigned int uint32;
typedef __attribute__((ext_vector_type(8))) short short8;   // 8 bf16 (4 VGPRs)
typedef __attribute__((ext_vector_type(4))) float f32x4;

// fp32 -> bf16 bits, round-to-nearest-even (finite inputs)
__device__ inline unsigned short f2b(float f) {
    uint32 x = __float_as_uint(f);
    uint32 r = x + 0x7fffu + ((x >> 16) & 1u);
    return (unsigned short)(r >> 16);
}
__device__ inline float blo(uint32 u) { return __uint_as_float(u << 16); }
__device__ inline float bhi(uint32 u) { return __uint_as_float(u & 0xffff0000u); }

// ---------------- phase 1: scatter edges into (bucket, sub) append regions ----------------
__global__ __launch_bounds__(256) void k_scatter(const int* __restrict__ src, const int* __restrict__ dst,
                                                 int* __restrict__ cur, uint32* __restrict__ bbuf) {
    int e = blockIdx.x * 256 + threadIdx.x;
    int sub = blockIdx.x & (NSUB - 1);
    if (e < N_EDGES) {
        int s = src[e], d = dst[e];
        int b = d >> BSHIFT;
        int slot = (b << 3) | sub;
        int p = atomicAdd(&cur[slot * CURSTRIDE], 1);
        if (p < SUBCAP)
            bbuf[slot * SUBCAP + p] = (uint32)(((d & 63) << 17) | s);
    }
}

// ---------------- exclusive scan of bucket totals -> bucketBase, + offsets[N] ----------------
__global__ __launch_bounds__(256) void k_bucketscan(const int* __restrict__ cur, int* __restrict__ bucketBase,
                                                    int* __restrict__ offsets) {
    __shared__ int wsum[4];
    int t = threadIdx.x;
    int v[7];
    int ts = 0;
    #pragma unroll
    for (int i = 0; i < 7; ++i) {
        int b = t * 7 + i;
        int sz = 0;
        if (b < NBUCK) {
            #pragma unroll
            for (int s = 0; s < NSUB; ++s) {
                int c = cur[((b << 3) | s) * CURSTRIDE];
                sz += (c < SUBCAP) ? c : SUBCAP;
            }
        }
        v[i] = sz;
        ts += sz;
    }
    int lane = t & 63, w = t >> 6;
    int inc = ts;
    #pragma unroll
    for (int d = 1; d < 64; d <<= 1) {
        int u = __shfl_up(inc, d, 64);
        if (lane >= d) inc += u;
    }
    if (lane == 63) wsum[w] = inc;
    __syncthreads();
    int wpre = 0;
    for (int i = 0; i < w; ++i) wpre += wsum[i];
    int run = wpre + inc - ts;
    #pragma unroll
    for (int i = 0; i < 7; ++i) {
        int b = t * 7 + i;
        if (b < NBUCK) bucketBase[b] = run;
        run += v[i];
    }
    if (t == 255) offsets[N_NODES] = run;   // == N_EDGES
}

// ---------------- phase 2: per-bucket local sort -> coalesced CSR + dinv + offsets ----------------
__global__ __launch_bounds__(256) void k_build(const uint32* __restrict__ bbuf, const int* __restrict__ cur,
                                               const int* __restrict__ bucketBase, int* __restrict__ col,
                                               int* __restrict__ offsets, float* __restrict__ dinv) {
    int b = blockIdx.x;
    __shared__ uint32 ebuf[NSUB * SUBCAP];    // 8 KB
    __shared__ int sorted[NSUB * SUBCAP];     // 8 KB
    __shared__ int hist[64], lcur[64];
    __shared__ int subOff[NSUB + 1];
    int t = threadIdx.x;
    if (t == 0) {
        int run = 0;
        #pragma unroll
        for (int s = 0; s < NSUB; ++s) {
            subOff[s] = run;
            int c = cur[((b << 3) | s) * CURSTRIDE];
            run += (c < SUBCAP) ? c : SUBCAP;
        }
        subOff[NSUB] = run;
    }
    if (t < 64) hist[t] = 0;
    __syncthreads();
    int cnt = subOff[NSUB];
    #pragma unroll
    for (int s = 0; s < NSUB; ++s) {
        int n = subOff[s + 1] - subOff[s];
        const uint32* p = bbuf + ((b << 3) | s) * SUBCAP;
        for (int i = t; i < n; i += 256) ebuf[subOff[s] + i] = p[i];
    }
    __syncthreads();
    for (int i = t; i < cnt; i += 256) atomicAdd(&hist[ebuf[i] >> 17], 1);
    __syncthreads();
    int nb = b << BSHIFT;
    if (t < 64) {   // wave 0: scan 64 counts, emit offsets + dinv
        int c = hist[t];
        int inc = c;
        #pragma unroll
        for (int d = 1; d < 64; d <<= 1) {
            int u = __shfl_up(inc, d, 64);
            if (t >= d) inc += u;
        }
        int excl = inc - c;
        lcur[t] = excl;
        int node = nb + t;
        if (node < N_NODES) {
            offsets[node] = bucketBase[b] + excl;
            dinv[node] = rsqrtf((float)(c + 1));
        }
    }
    __syncthreads();
    for (int i = t; i < cnt; i += 256) {
        uint32 p = ebuf[i];
        int lp = atomicAdd(&lcur[p >> 17], 1);
        sorted[lp] = (int)(p & 0x1FFFF);
    }
    __syncthreads();
    int base = bucketBase[b];
    for (int i = t; i < cnt; i += 256) col[base + i] = sorted[i];
}

// ---------------- cast + transpose W1,W2,W3 -> WT bf16 [layer][n][k] ----------------
__global__ __launch_bounds__(256) void k_castw(const float* __restrict__ W1, const float* __restrict__ W2,
                                               const float* __restrict__ W3, unsigned short* __restrict__ WT) {
    int i = blockIdx.x * blockDim.x + threadIdx.x;   // 3*16384
    if (i >= 3 * NFEAT * NFEAT) return;
    int l = i >> 14;
    int j = i & 16383;
    int n = j >> 7;
    int k = j & 127;
    const float* W = (l == 0) ? W1 : (l == 1) ? W2 : W3;
    WT[i] = f2b(W[k * NFEAT + n]);   // WT[l][n*128+k] = W[k][n]
}

// ---------------- bf16 MFMA GEMM: C[M,128] = A[M,128] @ W ----------------
#define WT_STRIDE 136
__global__ __launch_bounds__(256) void k_gemm(const unsigned short* __restrict__ A,
                                              const unsigned short* __restrict__ WTl,
                                              unsigned short* __restrict__ C, int M) {
    __shared__ unsigned short sWT[NFEAT * WT_STRIDE];   // 34 KB
    int t = threadIdx.x;
    for (int i = t; i < NFEAT * 16; i += 256) {
        int n = i >> 4, c = i & 15;
        *(float4*)(sWT + n * WT_STRIDE + c * 8) = ((const float4*)WTl)[i];
    }
    int wave = t >> 6, lane = t & 63;
    int m0 = blockIdx.x * 64 + wave * 16;
    int mRow = m0 + (lane & 15);
    if (mRow >= M) mRow = M - 1;
    int kg = lane >> 4;
    const short8* Ap = (const short8*)(A + (size_t)mRow * NFEAT + kg * 8);
    short8 a0 = Ap[0];
    short8 a1 = Ap[4];
    short8 a2 = Ap[8];
    short8 a3 = Ap[12];
    __syncthreads();

    f32x4 acc[8];
    #pragma unroll
    for (int nt = 0; nt < 8; ++nt) acc[nt] = (f32x4){0.f, 0.f, 0.f, 0.f};

    #pragma unroll
    for (int nt = 0; nt < 8; ++nt) {
        int n = nt * 16 + (lane & 15);
        const short8* Bp = (const short8*)(sWT + n * WT_STRIDE + kg * 8);
        short8 b0 = Bp[0];
        short8 b1 = Bp[4];
        short8 b2 = Bp[8];
        short8 b3 = Bp[12];
        acc[nt] = __builtin_amdgcn_mfma_f32_16x16x32_bf16(a0, b0, acc[nt], 0, 0, 0);
        acc[nt] = __builtin_amdgcn_mfma_f32_16x16x32_bf16(a1, b1, acc[nt], 0, 0, 0);
        acc[nt] = __builtin_amdgcn_mfma_f32_16x16x32_bf16(a2, b2, acc[nt], 0, 0, 0);
        acc[nt] = __builtin_amdgcn_mfma_f32_16x16x32_bf16(a3, b3, acc[nt], 0, 0, 0);
    }

    int colBase = lane & 15;
    #pragma unroll
    for (int r = 0; r < 4; ++r) {
        int gr = m0 + kg * 4 + r;
        if (gr < M) {
            unsigned short* Cp = C + (size_t)gr * NFEAT + colBase;
            #pragma unroll
            for (int nt = 0; nt < 8; ++nt) Cp[nt * 16] = f2b(acc[nt][r]);
        }
    }
}

// ---------------- same GEMM but A is fp32 (layer 1: fuses the x->bf16 cast) ----------------
__device__ inline short8 cvt8(const float* p) {
    float4 v0 = ((const float4*)p)[0];
    float4 v1 = ((const float4*)p)[1];
    short8 r;
    r[0] = (short)f2b(v0.x); r[1] = (short)f2b(v0.y);
    r[2] = (short)f2b(v0.z); r[3] = (short)f2b(v0.w);
    r[4] = (short)f2b(v1.x); r[5] = (short)f2b(v1.y);
    r[6] = (short)f2b(v1.z); r[7] = (short)f2b(v1.w);
    return r;
}

__global__ __launch_bounds__(256) void k_gemm_x(const float* __restrict__ A,
                                                const unsigned short* __restrict__ WTl,
                                                unsigned short* __restrict__ C, int M) {
    __shared__ unsigned short sWT[NFEAT * WT_STRIDE];   // 34 KB
    int t = threadIdx.x;
    for (int i = t; i < NFEAT * 16; i += 256) {
        int n = i >> 4, c = i & 15;
        *(float4*)(sWT + n * WT_STRIDE + c * 8) = ((const float4*)WTl)[i];
    }
    int wave = t >> 6, lane = t & 63;
    int m0 = blockIdx.x * 64 + wave * 16;
    int mRow = m0 + (lane & 15);
    if (mRow >= M) mRow = M - 1;
    int kg = lane >> 4;
    const float* Ap = A + (size_t)mRow * NFEAT + kg * 8;
    short8 a0 = cvt8(Ap);
    short8 a1 = cvt8(Ap + 32);
    short8 a2 = cvt8(Ap + 64);
    short8 a3 = cvt8(Ap + 96);
    __syncthreads();

    f32x4 acc[8];
    #pragma unroll
    for (int nt = 0; nt < 8; ++nt) acc[nt] = (f32x4){0.f, 0.f, 0.f, 0.f};

    #pragma unroll
    for (int nt = 0; nt < 8; ++nt) {
        int n = nt * 16 + (lane & 15);
        const short8* Bp = (const short8*)(sWT + n * WT_STRIDE + kg * 8);
        short8 b0 = Bp[0];
        short8 b1 = Bp[4];
        short8 b2 = Bp[8];
        short8 b3 = Bp[12];
        acc[nt] = __builtin_amdgcn_mfma_f32_16x16x32_bf16(a0, b0, acc[nt], 0, 0, 0);
        acc[nt] = __builtin_amdgcn_mfma_f32_16x16x32_bf16(a1, b1, acc[nt], 0, 0, 0);
        acc[nt] = __builtin_amdgcn_mfma_f32_16x16x32_bf16(a2, b2, acc[nt], 0, 0, 0);
        acc[nt] = __builtin_amdgcn_mfma_f32_16x16x32_bf16(a3, b3, acc[nt], 0, 0, 0);
    }

    int colBase = lane & 15;
    #pragma unroll
    for (int r = 0; r < 4; ++r) {
        int gr = m0 + kg * 4 + r;
        if (gr < M) {
            unsigned short* Cp = C + (size_t)gr * NFEAT + colBase;
            #pragma unroll
            for (int nt = 0; nt < 8; ++nt) Cp[nt * 16] = f2b(acc[nt][r]);
        }
    }
}

// ---------------- aggregation core v2: coalesced metadata + shfl broadcast ----------------
// Per node: ONE lane-per-edge load of col (chunk of 64), per-lane w = dn*dinv[c],
// then broadcast (c,w) via cross-lane shfl (no memory, no dependent addr chain);
// row gathers stay 8-deep in flight.
#define AGG_BODY \
    float dn = dinv[n]; \
    uint32 v = XWu[(size_t)n * 64 + lane]; \
    float ax = dn * dn * blo(v); \
    float ay = dn * dn * bhi(v); \
    int e0 = off[n], e1 = off[n + 1]; \
    for (int base = e0; base < e1; base += 64) { \
        int len = e1 - base; if (len > 64) len = 64; \
        int cm = (lane < len) ? col[base + lane] : 0; \
        float wm = (lane < len) ? dn * dinv[cm] : 0.f; \
        int j = 0; \
        for (; j + 8 <= len; j += 8) { \
            int cc0 = __shfl(cm, j + 0, 64); int cc1 = __shfl(cm, j + 1, 64); \
            int cc2 = __shfl(cm, j + 2, 64); int cc3 = __shfl(cm, j + 3, 64); \
            int cc4 = __shfl(cm, j + 4, 64); int cc5 = __shfl(cm, j + 5, 64); \
            int cc6 = __shfl(cm, j + 6, 64); int cc7 = __shfl(cm, j + 7, 64); \
            float w0 = __shfl(wm, j + 0, 64); float w1 = __shfl(wm, j + 1, 64); \
            float w2 = __shfl(wm, j + 2, 64); float w3 = __shfl(wm, j + 3, 64); \
            float w4 = __shfl(wm, j + 4, 64); float w5 = __shfl(wm, j + 5, 64); \
            float w6 = __shfl(wm, j + 6, 64); float w7 = __shfl(wm, j + 7, 64); \
            uint32 u0 = XWu[(size_t)cc0 * 64 + lane]; \
            uint32 u1 = XWu[(size_t)cc1 * 64 + lane]; \
            uint32 u2 = XWu[(size_t)cc2 * 64 + lane]; \
            uint32 u3 = XWu[(size_t)cc3 * 64 + lane]; \
            uint32 u4 = XWu[(size_t)cc4 * 64 + lane]; \
            uint32 u5 = XWu[(size_t)cc5 * 64 + lane]; \
            uint32 u6 = XWu[(size_t)cc6 * 64 + lane]; \
            uint32 u7 = XWu[(size_t)cc7 * 64 + lane]; \
            ax = fmaf(w0, blo(u0), ax); ay = fmaf(w0, bhi(u0), ay); \
            ax = fmaf(w1, blo(u1), ax); ay = fmaf(w1, bhi(u1), ay); \
            ax = fmaf(w2, blo(u2), ax); ay = fmaf(w2, bhi(u2), ay); \
            ax = fmaf(w3, blo(u3), ax); ay = fmaf(w3, bhi(u3), ay); \
            ax = fmaf(w4, blo(u4), ax); ay = fmaf(w4, bhi(u4), ay); \
            ax = fmaf(w5, blo(u5), ax); ay = fmaf(w5, bhi(u5), ay); \
            ax = fmaf(w6, blo(u6), ax); ay = fmaf(w6, bhi(u6), ay); \
            ax = fmaf(w7, blo(u7), ax); ay = fmaf(w7, bhi(u7), ay); \
        } \
        for (; j < len; ++j) { \
            int cc = __shfl(cm, j, 64); \
            float ww = __shfl(wm, j, 64); \
            uint32 u = XWu[(size_t)cc * 64 + lane]; \
            ax = fmaf(ww, blo(u), ax); ay = fmaf(ww, bhi(u), ay); \
        } \
    }

__global__ __launch_bounds__(256) void k_agg(const uint32* __restrict__ XWu, const int* __restrict__ col,
                                             const int* __restrict__ off, const float* __restrict__ dinv,
                                             const float* __restrict__ bias, uint32* __restrict__ Hu) {
    int wid = (blockIdx.x * blockDim.x + threadIdx.x) >> 6;
    int lane = threadIdx.x & 63;
    if (wid >= N_NODES) return;
    int n = wid;
    AGG_BODY
    float2 bb = ((const float2*)bias)[lane];
    float ox = fmaxf(ax + bb.x, 0.f);
    float oy = fmaxf(ay + bb.y, 0.f);
    Hu[(size_t)n * 64 + lane] = (uint32)f2b(ox) | ((uint32)f2b(oy) << 16);
}

// ---------------- layer-3 aggregation + relu + FC dot -> per-node scalar ----------------
__global__ __launch_bounds__(256) void k_agg_fc(const uint32* __restrict__ XWu, const int* __restrict__ col,
                                                const int* __restrict__ off, const float* __restrict__ dinv,
                                                const float* __restrict__ bias, const float* __restrict__ Wfc,
                                                float* __restrict__ nodeS) {
    int wid = (blockIdx.x * blockDim.x + threadIdx.x) >> 6;
    int lane = threadIdx.x & 63;
    if (wid >= N_NODES) return;
    int n = wid;
    AGG_BODY
    float2 bb = ((const float2*)bias)[lane];
    float hx = fmaxf(ax + bb.x, 0.f);
    float hy = fmaxf(ay + bb.y, 0.f);
    float2 wf = ((const float2*)Wfc)[lane];
    float s = hx * wf.x + hy * wf.y;
    for (int d = 32; d > 0; d >>= 1) s += __shfl_down(s, d, 64);
    if (lane == 0) nodeS[n] = s;
}

// ---------------- segment mean over sorted batch + bias (one block per graph) ----------------
__device__ inline int lower_bound_dev(const int* a, int n, int key) {
    int lo = 0, hi = n;
    while (lo < hi) {
        int mid = (lo + hi) >> 1;
        if (a[mid] < key) lo = mid + 1; else hi = mid;
    }
    return lo;
}

__global__ __launch_bounds__(256) void k_pool(const float* __restrict__ nodeS, const int* __restrict__ batch,
                                              const float* __restrict__ bfc, float* __restrict__ out) {
    int g = blockIdx.x;
    int t = threadIdx.x;
    int lo = lower_bound_dev(batch, N_NODES, g);
    int hi = lower_bound_dev(batch, N_NODES, g + 1);
    float s = 0.f;
    for (int i = lo + t; i < hi; i += 256) s += nodeS[i];
    for (int d = 32; d > 0; d >>= 1) s += __shfl_down(s, d, 64);
    __shared__ float ws[4];
    int lane = t & 63, w = t >> 6;
    if (lane == 0) ws[w] = s;
    __syncthreads();
    if (t == 0) {
        float tot = ws[0] + ws[1] + ws[2] + ws[3];
        float cnt = (float)(hi - lo);
        out[g] = tot / fmaxf(cnt, 1.0f) + bfc[0];
    }
}

// ---------------- launch ----------------
extern "C" void kernel_launch(void* const* d_in, const int* in_sizes, int n_in,
                              void* d_out, int out_size, void* d_ws, size_t ws_size,
                              hipStream_t stream) {
    const float* x    = (const float*)d_in[0];
    const int*   ei   = (const int*)d_in[1];     // [2, E] : row0 = src, row1 = dst
    const int*   batch= (const int*)d_in[2];
    const float* W1   = (const float*)d_in[3];
    const float* b1   = (const float*)d_in[4];
    const float* W2   = (const float*)d_in[5];
    const float* b2   = (const float*)d_in[6];
    const float* W3   = (const float*)d_in[7];
    const float* b3   = (const float*)d_in[8];
    const float* Wfc  = (const float*)d_in[9];
    const float* bfc  = (const float*)d_in[10];
    float* out = (float*)d_out;

    const int* src = ei;
    const int* dst = ei + N_EDGES;

    // carve workspace (256B-aligned)
    char* p = (char*)d_ws;
    auto carve = [&](size_t bytes) { void* r = (void*)p; p += (bytes + 255) & ~(size_t)255; return r; };
    int*    cur       = (int*)   carve(sizeof(int) * (size_t)NBUCK * NSUB * CURSTRIDE);   // 800 KB
    uint32* bbuf      = (uint32*)carve(sizeof(uint32) * (size_t)NBUCK * NSUB * SUBCAP);   // 12.8 MB
    int*    bucketBase= (int*)   carve(sizeof(int) * (NBUCK + 1));
    float*  dinv      = (float*) carve(sizeof(float) * N_NODES);
    int*    offsets   = (int*)   carve(sizeof(int) * (N_NODES + 1));
    int*    col       = (int*)   carve(sizeof(int) * N_EDGES);
    unsigned short* XW = (unsigned short*)carve(sizeof(short) * (size_t)N_NODES * NFEAT);
    unsigned short* H  = (unsigned short*)carve(sizeof(short) * (size_t)N_NODES * NFEAT);
    unsigned short* WT = (unsigned short*)carve(sizeof(short) * 3 * NFEAT * NFEAT);
    float* nodeS      = (float*) carve(sizeof(float) * N_NODES);

    const int edgeBlocks = (N_EDGES + 255) / 256;            // 6250
    const int waveNodeBlocks = (N_NODES * 64 + 255) / 256;   // 25000
    const int gemmBlocks = (N_NODES + 63) / 64;              // 1563

    hipMemsetAsync(cur, 0, sizeof(int) * (size_t)NBUCK * NSUB * CURSTRIDE, stream);
    k_scatter<<<edgeBlocks, 256, 0, stream>>>(src, dst, cur, bbuf);
    k_bucketscan<<<1, 256, 0, stream>>>(cur, bucketBase, offsets);
    k_build<<<NBUCK, 256, 0, stream>>>(bbuf, cur, bucketBase, col, offsets, dinv);

    k_castw<<<(3 * NFEAT * NFEAT + 255) / 256, 256, 0, stream>>>(W1, W2, W3, WT);

    // layer 1 (cast fused into GEMM A-load)
    k_gemm_x<<<gemmBlocks, 256, 0, stream>>>(x, WT, XW, N_NODES);
    k_agg<<<waveNodeBlocks, 256, 0, stream>>>((const uint32*)XW, col, offsets, dinv, b1, (uint32*)H);
    // layer 2
    k_gemm<<<gemmBlocks, 256, 0, stream>>>(H, WT + NFEAT * NFEAT, XW, N_NODES);
    k_agg<<<waveNodeBlocks, 256, 0, stream>>>((const uint32*)XW, col, offsets, dinv, b2, (uint32*)H);
    // layer 3
    k_gemm<<<gemmBlocks, 256, 0, stream>>>(H, WT + 2 * NFEAT * NFEAT, XW, N_NODES);
    k_agg_fc<<<waveNodeBlocks, 256, 0, stream>>>((const uint32*)XW, col, offsets, dinv, b3, Wfc, nodeS);

    k_pool<<<N_GRAPHS, 256, 0, stream>>>(nodeS, batch, bfc, out);
}